// Round 10
// baseline (245.136 us; speedup 1.0000x reference)
//
#include <hip/hip_runtime.h>
#include <hip/hip_bf16.h>
#include <cstdint>
#include <cstddef>

// Problem constants (fixed by reference)
#define NE 8      // experts
#define MEt 1024  // tokens per expert
#define KD 2048   // in features
#define ND 2048   // out features
#define NG 16     // K / G  (G = 128)

// Fused tile config
#define BM 256
#define BN 128
#define BK 128            // one scale-group per K-step
#define NKT (KD / BK)     // 16 K-steps

typedef int   i32x4  __attribute__((ext_vector_type(4)));
typedef int   i32x16 __attribute__((ext_vector_type(16)));
typedef float f32x16 __attribute__((ext_vector_type(16)));

__device__ __forceinline__ unsigned pack4(int x0, int x1, int x2, int x3) {
    return (unsigned)(x0 & 0xFF) | ((unsigned)(x1 & 0xFF) << 8) |
           ((unsigned)(x2 & 0xFF) << 16) | ((unsigned)x3 << 24);
}

// Fused W4A8 grouped GEMM: int32->int8 pack inlined in the staging pipeline.
// 512 blocks (8e x 4tm x 16tn), 512 threads (8 waves, 4m x 2n, 64x64 per wave).
// One barrier per K-step: reads hit buf c while writes fill buf c^1.
__global__ __launch_bounds__(512, 2)
void w4a8_fused(const int* __restrict__ a_q,        // [M, K] int8-in-int32
                const int* __restrict__ w_q,        // [E, N, K] int4-in-int32
                const float* __restrict__ per_tok,  // [M]
                const float* __restrict__ per_chan, // [E, N]
                const float* __restrict__ wgs,      // [E, N, NG]
                float* __restrict__ out)            // [M, N] fp32
{
    // K-major packed LDS: A[kc][row] 8*256*16 = 32KB ; W[kc][row] 8*128*16 = 16KB
    __shared__ __align__(16) unsigned char As[2][BK / 16 * BM * 16];
    __shared__ __align__(16) unsigned char Ws[2][BK / 16 * BN * 16];
    __shared__ float scs[NG][BN];   // 8 KB

    // XCD-chunked swizzle: 512 blocks, 64 per XCD -> one expert per XCD
    int bid = blockIdx.x;
    int b2  = (bid & 7) * 64 + (bid >> 3);
    const int e  = b2 >> 6;        // 0..7
    const int tm = (b2 >> 4) & 3;  // 0..3
    const int tn = b2 & 15;        // 0..15

    const int tid  = threadIdx.x;
    const int lane = tid & 63;
    const int wv   = tid >> 6;   // 0..7
    const int wm   = wv >> 1;    // 0..3  (64-row band)
    const int wn   = wv & 1;     // 0..1  (64-col band)
    const int lcol = lane & 31;
    const int lhi  = lane >> 5;

    const int* Ag = a_q + (size_t)(e * MEt + tm * BM) * KD;
    const int* Wg = w_q + ((size_t)e * ND + tn * BN) * KD;

    // staging task decomposition (per thread):
    //   A: 4 tasks, taskid = tid + j*512 -> arow = id & 255, akc = id >> 8
    //   W: 2 tasks, taskid = tid + j*512 -> wrow = id & 127, wkc = id >> 7
    int arow[4], akc[4], wrow[2], wkc[2];
#pragma unroll
    for (int j = 0; j < 4; ++j) { int id = tid + j * 512; arow[j] = id & 255; akc[j] = id >> 8; }
#pragma unroll
    for (int j = 0; j < 2; ++j) { int id = tid + j * 512; wrow[j] = id & 127; wkc[j] = id >> 7; }

    i32x4 av[4][4], wvv[2][4];

#define ISSUE_LOADS(kt)                                                              \
    {                                                                                \
        _Pragma("unroll")                                                            \
        for (int j = 0; j < 4; ++j) {                                                \
            const int* gp = Ag + (size_t)arow[j] * KD + (kt) * BK + akc[j] * 16;     \
            av[j][0] = *(const i32x4*)(gp);      av[j][1] = *(const i32x4*)(gp + 4); \
            av[j][2] = *(const i32x4*)(gp + 8);  av[j][3] = *(const i32x4*)(gp + 12);\
        }                                                                            \
        _Pragma("unroll")                                                            \
        for (int j = 0; j < 2; ++j) {                                                \
            const int* gp = Wg + (size_t)wrow[j] * KD + (kt) * BK + wkc[j] * 16;     \
            wvv[j][0] = *(const i32x4*)(gp);     wvv[j][1] = *(const i32x4*)(gp + 4);\
            wvv[j][2] = *(const i32x4*)(gp + 8); wvv[j][3] = *(const i32x4*)(gp + 12);\
        }                                                                            \
    }

#define PACK_WRITE(buf)                                                              \
    {                                                                                \
        _Pragma("unroll")                                                            \
        for (int j = 0; j < 4; ++j) {                                                \
            i32x4 pk;                                                                \
            pk[0] = (int)pack4(av[j][0][0], av[j][0][1], av[j][0][2], av[j][0][3]);  \
            pk[1] = (int)pack4(av[j][1][0], av[j][1][1], av[j][1][2], av[j][1][3]);  \
            pk[2] = (int)pack4(av[j][2][0], av[j][2][1], av[j][2][2], av[j][2][3]);  \
            pk[3] = (int)pack4(av[j][3][0], av[j][3][1], av[j][3][2], av[j][3][3]);  \
            *(i32x4*)&As[buf][akc[j] * (BM * 16) + arow[j] * 16] = pk;               \
        }                                                                            \
        _Pragma("unroll")                                                            \
        for (int j = 0; j < 2; ++j) {                                                \
            i32x4 pk;                                                                \
            pk[0] = (int)pack4(wvv[j][0][0], wvv[j][0][1], wvv[j][0][2], wvv[j][0][3]); \
            pk[1] = (int)pack4(wvv[j][1][0], wvv[j][1][1], wvv[j][1][2], wvv[j][1][3]); \
            pk[2] = (int)pack4(wvv[j][2][0], wvv[j][2][1], wvv[j][2][2], wvv[j][2][3]); \
            pk[3] = (int)pack4(wvv[j][3][0], wvv[j][3][1], wvv[j][3][2], wvv[j][3][3]); \
            *(i32x4*)&Ws[buf][wkc[j] * (BN * 16) + wrow[j] * 16] = pk;               \
        }                                                                            \
    }

    f32x16 facc[2][2] = {};
    const i32x16 z16 = {};

    // ---- prologue: stage tile 0 into buf 0, load all group scales ----
    ISSUE_LOADS(0)
    PACK_WRITE(0)
#pragma unroll
    for (int i = 0; i < 4; ++i) {
        int idx = tid + i * 512;
        int g = idx >> 7, n = idx & 127;
        scs[g][n] = wgs[((size_t)e * ND + tn * BN + n) * NG + g];
    }
    __syncthreads();

    int c = 0;
    for (int kt = 0; kt < NKT; ++kt) {
        // T14: issue next tile's global loads FIRST (latency hides under compute)
        if (kt + 1 < NKT) {
            ISSUE_LOADS(kt + 1)
            __builtin_amdgcn_sched_barrier(0);  // keep the load cluster here
        }

        const unsigned char* Ac = As[c];
        const unsigned char* Wc = Ws[c];
        float sc0 = scs[kt][wn * 64 +  0 + lcol];
        float sc1 = scs[kt][wn * 64 + 32 + lcol];

        // fragments: lane-consecutive 16B reads, conflict-free
        i32x4 bfr[2][4];
#pragma unroll
        for (int ni = 0; ni < 2; ++ni)
#pragma unroll
            for (int ks = 0; ks < 4; ++ks) {
                int kch = ks * 2 + lhi;
                bfr[ni][ks] = *(const i32x4*)&Wc[kch * (BN * 16) + (wn * 64 + ni * 32 + lcol) * 16];
            }
#pragma unroll
        for (int mi = 0; mi < 2; ++mi) {
            i32x4 afr[4];
#pragma unroll
            for (int ks = 0; ks < 4; ++ks) {
                int kch = ks * 2 + lhi;
                afr[ks] = *(const i32x4*)&Ac[kch * (BM * 16) + (wm * 64 + mi * 32 + lcol) * 16];
            }
            i32x16 acc0, acc1;
            acc0 = __builtin_amdgcn_mfma_i32_32x32x32_i8(afr[0], bfr[0][0], z16, 0, 0, 0);
            acc1 = __builtin_amdgcn_mfma_i32_32x32x32_i8(afr[0], bfr[1][0], z16, 0, 0, 0);
            acc0 = __builtin_amdgcn_mfma_i32_32x32x32_i8(afr[1], bfr[0][1], acc0, 0, 0, 0);
            acc1 = __builtin_amdgcn_mfma_i32_32x32x32_i8(afr[1], bfr[1][1], acc1, 0, 0, 0);
            acc0 = __builtin_amdgcn_mfma_i32_32x32x32_i8(afr[2], bfr[0][2], acc0, 0, 0, 0);
            acc1 = __builtin_amdgcn_mfma_i32_32x32x32_i8(afr[2], bfr[1][2], acc1, 0, 0, 0);
            acc0 = __builtin_amdgcn_mfma_i32_32x32x32_i8(afr[3], bfr[0][3], acc0, 0, 0, 0);
            acc1 = __builtin_amdgcn_mfma_i32_32x32x32_i8(afr[3], bfr[1][3], acc1, 0, 0, 0);
#pragma unroll
            for (int i = 0; i < 16; ++i) {
                facc[mi][0][i] += (float)acc0[i] * sc0;
                facc[mi][1][i] += (float)acc1[i] * sc1;
            }
        }

        // pack + write NEXT tile into the other buffer, then the single barrier
        if (kt + 1 < NKT) {
            PACK_WRITE(c ^ 1)
        }
        __syncthreads();
        c ^= 1;
    }

    // ---- epilogue: per-token / per-channel scales, fp32 store ----
    const float* ptok  = per_tok  + e * MEt + tm * BM;
    const float* pchan = per_chan + (size_t)e * ND + tn * BN;
    float* og = out + (size_t)(e * MEt + tm * BM) * ND + tn * BN;

#pragma unroll
    for (int mi = 0; mi < 2; ++mi) {
        int mb = wm * 64 + mi * 32;
#pragma unroll
        for (int ni = 0; ni < 2; ++ni) {
            int nn = wn * 64 + ni * 32 + lcol;
            float pc = pchan[nn];
#pragma unroll
            for (int rg = 0; rg < 16; ++rg) {
                int mr = mb + (rg & 3) + 8 * (rg >> 2) + 4 * lhi;
                float pt = ptok[mr];
                og[(size_t)mr * ND + nn] = facc[mi][ni][rg] * pt * pc;
            }
        }
    }
#undef ISSUE_LOADS
#undef PACK_WRITE
}

extern "C" void kernel_launch(void* const* d_in, const int* in_sizes, int n_in,
                              void* d_out, int out_size, void* d_ws, size_t ws_size,
                              hipStream_t stream) {
    const int*   a_q = (const int*)d_in[0];
    const int*   w_q = (const int*)d_in[1];
    const float* pt  = (const float*)d_in[2];
    const float* pc  = (const float*)d_in[3];
    const float* wg  = (const float*)d_in[4];
    float* out = (float*)d_out;

    // 8 experts * 4 m-tiles * 16 n-tiles = 512 blocks, 512 threads (8 waves)
    w4a8_fused<<<dim3(512), dim3(512), 0, stream>>>(a_q, w_q, pt, pc, wg, out);
}

// Round 11
// 105.403 us; speedup vs baseline: 2.3257x; 2.3257x over previous
//
#include <hip/hip_runtime.h>
#include <hip/hip_bf16.h>
#include <cstdint>
#include <cstddef>

// Problem constants (fixed by reference)
#define NE 8      // experts
#define MEt 1024  // tokens per expert
#define KD 2048   // in features
#define ND 2048   // out features
#define NG 16     // K / G  (G = 128)

// Tile config
#define BM 256
#define BN 256
#define BK 128            // one scale-group per K-step
#define NKT (KD / BK)     // 16 K-steps
#define TILE_B (BM * BK)  // 32768 bytes per packed tile (A and B same)

typedef int   i32x4  __attribute__((ext_vector_type(4)));
typedef int   i32x16 __attribute__((ext_vector_type(16)));
typedef float f32x16 __attribute__((ext_vector_type(16)));

#define A_ROWS (NE * MEt)   // 8192
#define W_ROWS (NE * ND)    // 16384
#define A_BYTES ((size_t)A_ROWS * KD)   // 16 MiB packed
#define PP_ROWS 8           // rows per prepack block

__device__ __forceinline__ unsigned pack4(int x0, int x1, int x2, int x3) {
    return (unsigned)(x0 & 0xFF) | ((unsigned)(x1 & 0xFF) << 8) |
           ((unsigned)(x2 & 0xFF) << 16) | ((unsigned)x3 << 24);
}

__device__ __forceinline__ void gl_lds16(const void* g, void* l) {
    // async global->LDS, 16B/lane. LDS dest: uniform base + lane*16 (HW).
    // Global src: per-lane address. Consumes NO VGPRs for the data.
    __builtin_amdgcn_global_load_lds(
        (const __attribute__((address_space(1))) void*)g,
        (__attribute__((address_space(3))) void*)l, 16, 0, 0);
}

// ---------------- prepack v7: global_load_lds staging (reg-allocator-proof MLP) ----------------
// Packed layout (unchanged): tile(panel p, kt) contiguous 32KB:
//   addr = (p*NKT + kt)*TILE_B + kc*4096 + row_in_panel*16 + (k&15),  kc = (k in K-step)/16
// Block (512 thr, 8 waves) packs 8 source rows (64KB int32 -> 16KB int8).
// Phase 1: 64 glds x 1KB, contiguous, zero VGPR -> all in flight (128KB/CU).
// Phase 2: b128 LDS reads, pack4, 8x128B-segment stores to tile layout.
__global__ __launch_bounds__(512)
void w4a8_prepack(const int* __restrict__ a_q, const int* __restrict__ w_q,
                  unsigned char* __restrict__ a8, unsigned char* __restrict__ w8)
{
    __shared__ __align__(16) int lbuf[PP_ROWS * KD];   // 64KB raw int32 rows

    const int b   = blockIdx.x;
    const int tid = threadIdx.x;
    const int* src;
    unsigned char* dst;
    int rowbase;
    if (b < A_ROWS / PP_ROWS) { src = a_q; dst = a8; rowbase = b * PP_ROWS; }
    else                      { src = w_q; dst = w8; rowbase = (b - A_ROWS / PP_ROWS) * PP_ROWS; }

    const int wv   = tid >> 6;
    const int lane = tid & 63;

    // ---- phase 1: stage 64KB (8 rows) via 64 async glds, 8 per wave ----
    const unsigned char* sb = (const unsigned char*)(src + (size_t)rowbase * KD);
    unsigned char* lb = (unsigned char*)lbuf;
#pragma unroll
    for (int i = 0; i < 8; ++i) {
        int chunk = wv * 8 + i;           // 0..63, 1KB each
        gl_lds16(sb + (size_t)chunk * 1024 + lane * 16, lb + chunk * 1024);
    }
    __syncthreads();   // compiler emits vmcnt(0) drain before s_barrier

    // ---- phase 2: transpose-pack out of LDS ----
    const int kc = lane >> 3;   // 0..7
    const int rr = lane & 7;    // 0..7
    const int p  = rowbase >> 8;     // panel (256 rows)
    const int r0 = rowbase & 255;    // row offset within panel
#pragma unroll
    for (int j = 0; j < 2; ++j) {
        int kt = j * 8 + wv;    // 0..15
        const int* lp = lbuf + rr * KD + kt * BK + kc * 16;
        i32x4 v0 = *(const i32x4*)(lp);
        i32x4 v1 = *(const i32x4*)(lp + 4);
        i32x4 v2 = *(const i32x4*)(lp + 8);
        i32x4 v3 = *(const i32x4*)(lp + 12);
        i32x4 pk;
        pk[0] = (int)pack4(v0[0], v0[1], v0[2], v0[3]);
        pk[1] = (int)pack4(v1[0], v1[1], v1[2], v1[3]);
        pk[2] = (int)pack4(v2[0], v2[1], v2[2], v2[3]);
        pk[3] = (int)pack4(v3[0], v3[1], v3[2], v3[3]);
        unsigned char* dp = dst + ((size_t)(p * NKT + kt) * TILE_B)
                                + (size_t)(kc * 4096 + (r0 + rr) * 16);
        *(i32x4*)dp = pk;
    }
}

// ---------------- main GEMM: 256x256 tile, 8 waves, glds staging, conflict-free LDS ----------------
// (unchanged from R9 — runs ~18us, near the 15.6us MFMA floor)
__device__ __forceinline__ void stage_tile(unsigned char* lds, const unsigned char* gtile,
                                           int wv, int lane) {
#pragma unroll
    for (int i = 0; i < 4; ++i) {
        int chunk = wv * 4 + i;
        gl_lds16(gtile + chunk * 1024 + lane * 16, lds + chunk * 1024);
    }
}

__global__ __launch_bounds__(512, 2)
void w4a8_gemm_pp(const unsigned char* __restrict__ a8,   // packed, tile-contiguous
                  const unsigned char* __restrict__ w8,
                  const float* __restrict__ per_tok,      // [M]
                  const float* __restrict__ per_chan,     // [E, N]
                  const float* __restrict__ wgs,          // [E, N, NG]
                  float* __restrict__ out)                // [M, N] fp32
{
    __shared__ __align__(16) unsigned char As[2][TILE_B];
    __shared__ __align__(16) unsigned char Bs[2][TILE_B];
    __shared__ float scs[NG][BN];

    // 256 blocks: XCD-chunked -> expert e on XCD e; 32 blocks per expert per XCD
    int bid = blockIdx.x;
    int b2  = (bid & 7) * 32 + (bid >> 3);
    const int e  = b2 >> 5;        // 0..7
    const int tm = (b2 >> 3) & 3;  // 0..3 (256-row panels)
    const int tn = b2 & 7;         // 0..7 (256-col panels)

    const int tid  = threadIdx.x;
    const int lane = tid & 63;
    const int wv   = tid >> 6;   // 0..7
    const int wm   = wv >> 2;    // 0..1  (row half: 128 rows)
    const int wn   = wv & 3;     // 0..3  (col quarter: 64 cols)
    const int lcol = lane & 31;
    const int lhi  = lane >> 5;

    const unsigned char* Ag = a8 + (size_t)((e * 4 + tm) * NKT) * TILE_B;
    const unsigned char* Wg = w8 + (size_t)((e * 8 + tn) * NKT) * TILE_B;

    f32x16 facc[4][2] = {};
    const i32x16 z16 = {};

    // prologue: stage tile 0 + all group scales
    stage_tile(As[0], Ag, wv, lane);
    stage_tile(Bs[0], Wg, wv, lane);
#pragma unroll
    for (int i = 0; i < 8; ++i) {
        int idx = tid + i * 512;
        int g = idx >> 8, n = idx & 255;
        scs[g][n] = wgs[((size_t)e * ND + tn * BN + n) * NG + g];
    }
    __syncthreads();

    int c = 0;
    for (int kt = 0; kt < NKT; ++kt) {
        if (kt + 1 < NKT) {
            stage_tile(As[c ^ 1], Ag + (kt + 1) * TILE_B, wv, lane);
            stage_tile(Bs[c ^ 1], Wg + (kt + 1) * TILE_B, wv, lane);
        }
        const unsigned char* Ac = As[c];
        const unsigned char* Bc = Bs[c];

        float sc0 = scs[kt][wn * 64 +  0 + lcol];
        float sc1 = scs[kt][wn * 64 + 32 + lcol];

        // B fragments for this wave's 64 columns: [ni][ks], lane-consecutive 16B reads
        i32x4 bfr[2][4];
#pragma unroll
        for (int ni = 0; ni < 2; ++ni)
#pragma unroll
            for (int ks = 0; ks < 4; ++ks) {
                int kch = ks * 2 + lhi;
                bfr[ni][ks] = *(const i32x4*)&Bc[kch * (256 * 16) + (wn * 64 + ni * 32 + lcol) * 16];
            }

#pragma unroll
        for (int mi = 0; mi < 4; ++mi) {
            i32x4 afr[4];
#pragma unroll
            for (int ks = 0; ks < 4; ++ks) {
                int kch = ks * 2 + lhi;
                afr[ks] = *(const i32x4*)&Ac[kch * (256 * 16) + (wm * 128 + mi * 32 + lcol) * 16];
            }
            i32x16 acc0, acc1;
            acc0 = __builtin_amdgcn_mfma_i32_32x32x32_i8(afr[0], bfr[0][0], z16, 0, 0, 0);
            acc1 = __builtin_amdgcn_mfma_i32_32x32x32_i8(afr[0], bfr[1][0], z16, 0, 0, 0);
            acc0 = __builtin_amdgcn_mfma_i32_32x32x32_i8(afr[1], bfr[0][1], acc0, 0, 0, 0);
            acc1 = __builtin_amdgcn_mfma_i32_32x32x32_i8(afr[1], bfr[1][1], acc1, 0, 0, 0);
            acc0 = __builtin_amdgcn_mfma_i32_32x32x32_i8(afr[2], bfr[0][2], acc0, 0, 0, 0);
            acc1 = __builtin_amdgcn_mfma_i32_32x32x32_i8(afr[2], bfr[1][2], acc1, 0, 0, 0);
            acc0 = __builtin_amdgcn_mfma_i32_32x32x32_i8(afr[3], bfr[0][3], acc0, 0, 0, 0);
            acc1 = __builtin_amdgcn_mfma_i32_32x32x32_i8(afr[3], bfr[1][3], acc1, 0, 0, 0);
#pragma unroll
            for (int i = 0; i < 16; ++i) {
                facc[mi][0][i] += (float)acc0[i] * sc0;
                facc[mi][1][i] += (float)acc1[i] * sc1;
            }
        }
        __syncthreads();
        c ^= 1;
    }

    // epilogue: per-token and per-channel scales, store fp32
    const float* ptok  = per_tok  + e * MEt + tm * BM;
    const float* pchan = per_chan + (size_t)e * ND + tn * BN;
    float* og = out + (size_t)(e * MEt + tm * BM) * ND + tn * BN;

#pragma unroll
    for (int mi = 0; mi < 4; ++mi) {
        int mb = wm * 128 + mi * 32;
#pragma unroll
        for (int ni = 0; ni < 2; ++ni) {
            int nn = wn * 64 + ni * 32 + lcol;
            float pc = pchan[nn];
#pragma unroll
            for (int rg = 0; rg < 16; ++rg) {
                int mr = mb + (rg & 3) + 8 * (rg >> 2) + 4 * lhi;
                float pt = ptok[mr];
                og[(size_t)mr * ND + nn] = facc[mi][ni][rg] * pt * pc;
            }
        }
    }
}

extern "C" void kernel_launch(void* const* d_in, const int* in_sizes, int n_in,
                              void* d_out, int out_size, void* d_ws, size_t ws_size,
                              hipStream_t stream) {
    const int*   a_q = (const int*)d_in[0];
    const int*   w_q = (const int*)d_in[1];
    const float* pt  = (const float*)d_in[2];
    const float* pc  = (const float*)d_in[3];
    const float* wg  = (const float*)d_in[4];
    float* out = (float*)d_out;

    unsigned char* a8 = (unsigned char*)d_ws;
    unsigned char* w8 = a8 + A_BYTES;

    // (8192 + 16384) rows / 8 rows-per-block = 3072 blocks, 512 threads
    w4a8_prepack<<<dim3((A_ROWS + W_ROWS) / PP_ROWS), dim3(512), 0, stream>>>(a_q, w_q, a8, w8);
    // 8 experts * 4 m-tiles * 8 n-tiles = 256 blocks, 512 threads (8 waves)
    w4a8_gemm_pp<<<dim3(256), dim3(512), 0, stream>>>(a8, w8, pt, pc, wg, out);
}